// Round 1
// baseline (1572.220 us; speedup 1.0000x reference)
//
#include <hip/hip_runtime.h>
#include <hip/hip_bf16.h>
#include <hip/hip_fp16.h>

// Problem dims (fixed for QuantLlamaMLP_549755813920)
#define T_TOK 4096   // tokens = 2*2048
#define KDIM  4096   // in_features
#define IDIM  11008  // intermediate
#define ODIM  4096   // out_features

typedef _Float16 f16x8 __attribute__((ext_vector_type(8)));
typedef __fp16   h16x2 __attribute__((ext_vector_type(2)));  // cvt_pkrtz return type
typedef float    f32x4 __attribute__((ext_vector_type(4)));
typedef float    f32x2 __attribute__((ext_vector_type(2)));

// async global->LDS, 16B per lane; LDS dest = wave-uniform base + lane*16
__device__ __forceinline__ void glds16(const void* g, void* l) {
  __builtin_amdgcn_global_load_lds(
      (const __attribute__((address_space(1))) void*)g,
      (__attribute__((address_space(3))) void*)l, 16, 0, 0);
}

// ---------------- x: f32 -> f16 ----------------
__global__ void k_f32_to_f16(const float4* __restrict__ x,
                             ushort4* __restrict__ o, int n4) {
  int i = blockIdx.x * 256 + threadIdx.x;
  if (i >= n4) return;
  float4 v = x[i];
  __half h0 = __float2half(v.x), h1 = __float2half(v.y);
  __half h2v = __float2half(v.z), h3 = __float2half(v.w);
  ushort4 r;
  r.x = *(unsigned short*)&h0; r.y = *(unsigned short*)&h1;
  r.z = *(unsigned short*)&h2v; r.w = *(unsigned short*)&h3;
  o[i] = r;
}

// ------- repack int4 -> fp8 e4m3 (q-z), transposed to [N][K] --------------
// (q-z) in [-15,15] is EXACT in e4m3. Scale applied later in GEMM staging.
__global__ void k_repack_fp8(const int* __restrict__ qw,
                             const int* __restrict__ qz,
                             unsigned char* __restrict__ bq,
                             int K, int N) {
  __shared__ __align__(16) unsigned char tile[64][80];  // [n][k], 80%16==0
  const int n0 = blockIdx.x * 64;
  const int k0 = blockIdx.y * 64;
  const int t  = threadIdx.x;
  const int Nw = N >> 3;
  const int grp = k0 >> 7;  // 64-tile always within one 128-group
  const int jj = t & 7;
  const int zword = qz[(size_t)grp * Nw + (n0 >> 3) + jj];
#pragma unroll
  for (int r = 0; r < 2; ++r) {
    const int kk = (t >> 3) + r * 32;
    const int word = qw[(size_t)(k0 + kk) * Nw + (n0 >> 3) + jj];
#pragma unroll
    for (int i = 0; i < 8; i += 2) {
      const float v0 = (float)(((word >> (4 * i)) & 0xF) - ((zword >> (4 * i)) & 0xF));
      const float v1 = (float)(((word >> (4 * i + 4)) & 0xF) - ((zword >> (4 * i + 4)) & 0xF));
      const int p = __builtin_amdgcn_cvt_pk_fp8_f32(v0, v1, 0, false);
      tile[jj * 8 + i][kk]     = (unsigned char)(p & 0xFF);
      tile[jj * 8 + i + 1][kk] = (unsigned char)((p >> 8) & 0xFF);
    }
  }
  __syncthreads();
  const int n  = t >> 2;
  const int kc = (t & 3) * 16;
  int4 v = *(const int4*)&tile[n][kc];
  *(int4*)(bq + (size_t)(n0 + n) * K + k0 + kc) = v;
}

// dequant 16 fp8 (in uint4) * s -> 16 f16 stored at 16B-aligned dst
__device__ __forceinline__ void dq16(uint4 w, float s, __half* dst) {
  h16x2 r[8];
  const unsigned int ws[4] = {w.x, w.y, w.z, w.w};
#pragma unroll
  for (int d = 0; d < 4; ++d) {
    f32x2 lo = __builtin_amdgcn_cvt_pk_f32_fp8((int)ws[d], false);
    f32x2 hi = __builtin_amdgcn_cvt_pk_f32_fp8((int)ws[d], true);
    r[d * 2]     = __builtin_amdgcn_cvt_pkrtz(lo.x * s, lo.y * s);
    r[d * 2 + 1] = __builtin_amdgcn_cvt_pkrtz(hi.x * s, hi.y * s);
  }
  *(uint4*)dst       = *(const uint4*)&r[0];
  *(uint4*)(dst + 8) = *(const uint4*)&r[4];
}

// ============ R5: 256x256-tile, 8-wave, 8-phase counted-vmcnt GEMM =========
// C[M,N] = A[M,K] @ Bq[N,K]^T (fp8 B dequant in staging, f16 MFMA).
// Structure = the m201-class 8-phase schedule:
//   - per K-tile (BK=64): 4 phases, each {ds_read frag subtile | issue
//     globals} -> s_barrier -> lgkmcnt(0) -> setprio(1) 16xMFMA setprio(0)
//     -> s_barrier; junction stages next A tile via global_load_lds.
//   - vmcnt is COUNTED (always 7), never drained to 0 in the main loop:
//     steady outstanding = {scale,2xB}(3) + {4xA glds}(4) = 7.
//   - A LDS swizzle: 16B unit u of row stored at u^(row&7); achieved by
//     permuting the per-lane GLOBAL source (linear glds dest), and applying
//     the same XOR on fragment reads -> 2-way (free) instead of 8-way.
//   - B rows padded to 72 halves (144B) -> 2-way (free) on reads+writes.
// EPI 0: C f16 = acc; EPI 1: C f16 = silu(acc)*C; EPI 2: C f32 = acc
template <int EPI>
__global__ __launch_bounds__(512, 2)
void k_gemm_q(const __half* __restrict__ A,
              const unsigned char* __restrict__ Bq,
              const float* __restrict__ sc,
              void* __restrict__ Cv, int M, int N, int K) {
  __shared__ __align__(16) __half As[2][256 * 64];   // 64 KiB, linear+xor-swz
  __shared__ __align__(16) __half Bs[2][256 * 72];   // 72 KiB, padded rows

  const int ntiles = K >> 6;  // 64 (up/gate) or 172 (down); always even

  // ---- XCD-aware swizzle, then mb-fastest (B-panel reuse in XCD L2) ----
  // grids are 688 / 256, both % 8 == 0; M is always 4096 -> MB = 16.
  const int cpx = gridDim.x >> 3;
  const int bid = blockIdx.x;
  const int s2  = (bid & 7) * cpx + (bid >> 3);
  const int mb  = s2 & 15;
  const int nb  = s2 >> 4;
  const int m0 = mb << 8;
  const int n0 = nb << 8;

  const int t = threadIdx.x;
  const int w = t >> 6;         // wave 0..7
  const int lane = t & 63;
  const int quad = lane >> 4;
  const int lm = lane & 15;
  const int wm = w >> 2;        // 0..1  (row half: 128 rows)
  const int wn = w & 3;         // 0..3  (col quarter: 64 cols)

  f32x4 acc[8][4] = {};

  // ---- A staging (glds16, xor-swizzled global source) ----
  // round r: wave w covers rows r*64 + w*8 .. +8; lane l -> (row=l>>3, unit=l&7)
  const int arow_l = w * 8 + (lane >> 3);
  const int acol_l = ((lane & 7) ^ ((lane >> 3) & 7)) * 8;  // halves
  const __half* Agl = A + (size_t)(m0 + arow_l) * K + acol_l;
#define STAGE_A(BUF, KT) do {                                        \
    const __half* _ag = Agl + (size_t)(KT) * 64;                     \
    glds16(_ag,                   (void*)&As[BUF][(w * 8) * 64]);    \
    glds16(_ag + (size_t)64 * K,  (void*)&As[BUF][(64 + w * 8) * 64]);  \
    glds16(_ag + (size_t)128 * K, (void*)&As[BUF][(128 + w * 8) * 64]); \
    glds16(_ag + (size_t)192 * K, (void*)&As[BUF][(192 + w * 8) * 64]); \
  } while (0)

  // ---- B staging (reg dequant): thread -> (row = t>>1, half = t&1) ----
  const int brow = t >> 1;
  const int bhalf = t & 1;
  const unsigned char* bgl = Bq + (size_t)(n0 + brow) * K + bhalf * 32;
  const float* spl = sc + n0 + brow;
  __half* bwr0 = &Bs[0][brow * 72 + bhalf * 32];
  __half* bwr1 = &Bs[1][brow * 72 + bhalf * 32];

  // ---- fragment read offsets ----
  const int axor = lm & 7;
  const int arb = (wm * 128 + lm) * 64;            // halves
  const int au0 = ((quad ^ axor) & 7) * 8;         // kh=0 swizzled unit
  const int au1 = (((quad ^ axor) ^ 4) & 7) * 8;   // kh=1 swizzled unit
  const int brb = (wn * 64 + lm) * 72;             // halves

#define PH_BAR __builtin_amdgcn_s_barrier()
#define PH_LGKM do { asm volatile("s_waitcnt lgkmcnt(0)" ::: "memory"); \
                     __builtin_amdgcn_sched_barrier(0); } while (0)
#define WAIT_VM(NN) do { asm volatile("s_waitcnt vmcnt(" #NN ")" ::: "memory"); \
                         __builtin_amdgcn_sched_barrier(0); } while (0)

#define MFMA16(MI0, NI0, BF) do {                                          \
    __builtin_amdgcn_s_setprio(1);                                         \
    _Pragma("unroll")                                                      \
    for (int mi = 0; mi < 4; ++mi) {                                       \
      _Pragma("unroll")                                                    \
      for (int ni = 0; ni < 2; ++ni) {                                     \
        acc[(MI0) + mi][(NI0) + ni] = __builtin_amdgcn_mfma_f32_16x16x32_f16( \
            af[mi][0], BF[ni][0], acc[(MI0) + mi][(NI0) + ni], 0, 0, 0);   \
        acc[(MI0) + mi][(NI0) + ni] = __builtin_amdgcn_mfma_f32_16x16x32_f16( \
            af[mi][1], BF[ni][1], acc[(MI0) + mi][(NI0) + ni], 0, 0, 0);   \
      }                                                                    \
    }                                                                      \
    __builtin_amdgcn_s_setprio(0);                                         \
  } while (0)

// 4 phases: p0 {A[mq0](8 reads)+B[nq0](4) | issue scale+2B globals},
// p1 {B[nq1](4)}, p2 {A[mq1](8)}, p3 {vmcnt(7); dq -> other Bs buf}
#define GEMM_TILE(ASB, BSB, P0CODE, P3CODE) do {                           \
    f16x8 af[4][2], bf0[2][2], bf1[2][2];                                  \
    P0CODE                                                                 \
    __builtin_amdgcn_sched_barrier(0);                                     \
    _Pragma("unroll")                                                      \
    for (int mi = 0; mi < 4; ++mi) {                                       \
      af[mi][0] = *(const f16x8*)((ASB) + arb + mi * 1024 + au0);          \
      af[mi][1] = *(const f16x8*)((ASB) + arb + mi * 1024 + au1);          \
    }                                                                      \
    _Pragma("unroll")                                                      \
    for (int ni = 0; ni < 2; ++ni) {                                       \
      bf0[ni][0] = *(const f16x8*)((BSB) + brb + ni * 1152 + quad * 8);    \
      bf0[ni][1] = *(const f16x8*)((BSB) + brb + ni * 1152 + 32 + quad * 8); \
    }                                                                      \
    PH_BAR; PH_LGKM; MFMA16(0, 0, bf0); PH_BAR;                            \
    _Pragma("unroll")                                                      \
    for (int ni = 0; ni < 2; ++ni) {                                       \
      bf1[ni][0] = *(const f16x8*)((BSB) + brb + (2 + ni) * 1152 + quad * 8); \
      bf1[ni][1] = *(const f16x8*)((BSB) + brb + (2 + ni) * 1152 + 32 + quad * 8); \
    }                                                                      \
    PH_BAR; PH_LGKM; MFMA16(0, 2, bf1); PH_BAR;                            \
    _Pragma("unroll")                                                      \
    for (int mi = 0; mi < 4; ++mi) {                                       \
      af[mi][0] = *(const f16x8*)((ASB) + 4096 + arb + mi * 1024 + au0);   \
      af[mi][1] = *(const f16x8*)((ASB) + 4096 + arb + mi * 1024 + au1);   \
    }                                                                      \
    PH_BAR; PH_LGKM; MFMA16(4, 0, bf0); PH_BAR;                            \
    P3CODE                                                                 \
    PH_BAR; PH_LGKM; MFMA16(4, 2, bf1); PH_BAR;                            \
  } while (0)

  float sE, sO;
  uint4 bE0, bE1, bO0, bO1;

  // ---- prologue: ledger -> steady outstanding = 7 ----
  {
    float s00 = spl[0];
    uint4 a00 = *(const uint4*)(bgl);
    uint4 a01 = *(const uint4*)(bgl + 16);
    __builtin_amdgcn_sched_barrier(0);
    STAGE_A(0, 0);
    __builtin_amdgcn_sched_barrier(0);
    sO  = spl[0];                              // group (1)>>1 = 0
    bO0 = *(const uint4*)(bgl + 64);
    bO1 = *(const uint4*)(bgl + 64 + 16);
    __builtin_amdgcn_sched_barrier(0);
    STAGE_A(1, 1);
    WAIT_VM(11);                               // {s00, a00, a01} landed
    dq16(a00, s00, bwr0); dq16(a01, s00, bwr0 + 16);
    WAIT_VM(7);                                // A(0) landed; 7 remain
    asm volatile("s_waitcnt lgkmcnt(0)" ::: "memory");
    PH_BAR;
  }

  for (int pt = 0; pt < ntiles; pt += 2) {
    const int tE = (pt + 2 < ntiles) ? pt + 2 : ntiles - 1;
    const int tO = (pt + 3 < ntiles) ? pt + 3 : ntiles - 1;
    // ---- even tile pt: consume As[0]/Bs[0] ----
    GEMM_TILE(As[0], Bs[0],
      { sE  = spl[(size_t)(tE >> 1) * N];
        bE0 = *(const uint4*)(bgl + tE * 64);
        bE1 = *(const uint4*)(bgl + tE * 64 + 16); },
      { WAIT_VM(7);
        dq16(bO0, sO, bwr1); dq16(bO1, sO, bwr1 + 16); });
    STAGE_A(0, tE);
    WAIT_VM(7);                                // A(pt+1) landed
    PH_BAR;
    // ---- odd tile pt+1: consume As[1]/Bs[1] ----
    GEMM_TILE(As[1], Bs[1],
      { sO  = spl[(size_t)(tO >> 1) * N];
        bO0 = *(const uint4*)(bgl + tO * 64);
        bO1 = *(const uint4*)(bgl + tO * 64 + 16); },
      { WAIT_VM(7);
        dq16(bE0, sE, bwr0); dq16(bE1, sE, bwr0 + 16); });
    STAGE_A(1, tO);
    WAIT_VM(7);                                // A(pt+2) landed
    PH_BAR;
  }

  // ---- epilogue: C/D layout col = lane&15, row = quad*4 + reg ----
#pragma unroll
  for (int mi = 0; mi < 8; ++mi)
#pragma unroll
    for (int ni = 0; ni < 4; ++ni)
#pragma unroll
      for (int r = 0; r < 4; ++r) {
        const int row = m0 + wm * 128 + mi * 16 + quad * 4 + r;
        const int col = n0 + wn * 64 + ni * 16 + lm;
        const float v = acc[mi][ni][r];
        if (EPI == 0) {
          ((__half*)Cv)[(size_t)row * N + col] = __float2half(v);
        } else if (EPI == 1) {
          __half* H = (__half*)Cv;
          const float u = __half2float(H[(size_t)row * N + col]);
          const float sg = v / (1.0f + __expf(-v));
          H[(size_t)row * N + col] = __float2half(sg * u);
        } else {
          ((float*)Cv)[(size_t)row * N + col] = v;
        }
      }
#undef STAGE_A
#undef PH_BAR
#undef PH_LGKM
#undef WAIT_VM
#undef MFMA16
#undef GEMM_TILE
}

extern "C" void kernel_launch(void* const* d_in, const int* in_sizes, int n_in,
                              void* d_out, int out_size, void* d_ws, size_t ws_size,
                              hipStream_t stream) {
  const float* x   = (const float*)d_in[0];
  const int*   gqw = (const int*)d_in[1];
  const float* gsc = (const float*)d_in[2];
  const int*   gqz = (const int*)d_in[3];
  const int*   uqw = (const int*)d_in[4];
  const float* usc = (const float*)d_in[5];
  const int*   uqz = (const int*)d_in[6];
  const int*   dqw = (const int*)d_in[7];
  const float* dsc = (const float*)d_in[8];
  const int*   dqz = (const int*)d_in[9];
  float* out = (float*)d_out;

  // ws layout (~169 MB): xb (f16 x), bq (fp8 repack), h (f16 intermediate)
  char* ws = (char*)d_ws;
  __half*        xb = (__half*)ws;
  unsigned char* bq = (unsigned char*)(ws + 33554432);
  __half*        h  = (__half*)(ws + 33554432 + 45088768);

  k_f32_to_f16<<<16384, 256, 0, stream>>>((const float4*)x, (ushort4*)xb,
                                          (T_TOK * KDIM) / 4);

  dim3 rpg(IDIM / 64, KDIM / 64);    // (172, 64)
  dim3 rpd(ODIM / 64, IDIM / 64);    // (64, 172)
  const int g1 = (T_TOK / 256) * (IDIM / 256);  // 16*43 = 688 (%8==0)
  const int g2 = (T_TOK / 256) * (ODIM / 256);  // 16*16 = 256 (%8==0)

  // up: u = x @ Wu^T  -> h (f16)
  k_repack_fp8<<<rpg, 256, 0, stream>>>(uqw, uqz, bq, KDIM, IDIM);
  k_gemm_q<0><<<g1, 512, 0, stream>>>(xb, bq, usc, (void*)h, T_TOK, IDIM, KDIM);
  // gate: h = silu(x @ Wg^T) * h
  k_repack_fp8<<<rpg, 256, 0, stream>>>(gqw, gqz, bq, KDIM, IDIM);
  k_gemm_q<1><<<g1, 512, 0, stream>>>(xb, bq, gsc, (void*)h, T_TOK, IDIM, KDIM);
  // down: out = h @ Wd^T (f32)
  k_repack_fp8<<<rpd, 256, 0, stream>>>(dqw, dqz, bq, IDIM, ODIM);
  k_gemm_q<2><<<g2, 512, 0, stream>>>(h, bq, dsc, (void*)out, T_TOK, ODIM, IDIM);
}

// Round 2
// 1425.049 us; speedup vs baseline: 1.1033x; 1.1033x over previous
//
#include <hip/hip_runtime.h>
#include <hip/hip_bf16.h>
#include <hip/hip_fp16.h>

// Problem dims (fixed for QuantLlamaMLP_549755813920)
#define T_TOK 4096   // tokens = 2*2048
#define KDIM  4096   // in_features
#define IDIM  11008  // intermediate
#define ODIM  4096   // out_features

typedef _Float16 f16x8 __attribute__((ext_vector_type(8)));
typedef __fp16   h16x2 __attribute__((ext_vector_type(2)));  // cvt_pkrtz return type
typedef float    f32x4 __attribute__((ext_vector_type(4)));
typedef float    f32x2 __attribute__((ext_vector_type(2)));

// async global->LDS, 16B per lane; LDS dest = wave-uniform base + lane*16
__device__ __forceinline__ void glds16(const void* g, void* l) {
  __builtin_amdgcn_global_load_lds(
      (const __attribute__((address_space(1))) void*)g,
      (__attribute__((address_space(3))) void*)l, 16, 0, 0);
}

// ---------------- x: f32 -> f16 ----------------
__global__ void k_f32_to_f16(const float4* __restrict__ x,
                             ushort4* __restrict__ o, int n4) {
  int i = blockIdx.x * 256 + threadIdx.x;
  if (i >= n4) return;
  float4 v = x[i];
  __half h0 = __float2half(v.x), h1 = __float2half(v.y);
  __half h2v = __float2half(v.z), h3 = __float2half(v.w);
  ushort4 r;
  r.x = *(unsigned short*)&h0; r.y = *(unsigned short*)&h1;
  r.z = *(unsigned short*)&h2v; r.w = *(unsigned short*)&h3;
  o[i] = r;
}

// ------- repack int4 -> fp8 e4m3 (q-z), transposed to [N][K] --------------
// (q-z) in [-15,15] is EXACT in e4m3. Scale applied later in GEMM staging.
__global__ void k_repack_fp8(const int* __restrict__ qw,
                             const int* __restrict__ qz,
                             unsigned char* __restrict__ bq,
                             int K, int N) {
  __shared__ __align__(16) unsigned char tile[64][80];  // [n][k], 80%16==0
  const int n0 = blockIdx.x * 64;
  const int k0 = blockIdx.y * 64;
  const int t  = threadIdx.x;
  const int Nw = N >> 3;
  const int grp = k0 >> 7;  // 64-tile always within one 128-group
  const int jj = t & 7;
  const int zword = qz[(size_t)grp * Nw + (n0 >> 3) + jj];
#pragma unroll
  for (int r = 0; r < 2; ++r) {
    const int kk = (t >> 3) + r * 32;
    const int word = qw[(size_t)(k0 + kk) * Nw + (n0 >> 3) + jj];
#pragma unroll
    for (int i = 0; i < 8; i += 2) {
      const float v0 = (float)(((word >> (4 * i)) & 0xF) - ((zword >> (4 * i)) & 0xF));
      const float v1 = (float)(((word >> (4 * i + 4)) & 0xF) - ((zword >> (4 * i + 4)) & 0xF));
      const int p = __builtin_amdgcn_cvt_pk_fp8_f32(v0, v1, 0, false);
      tile[jj * 8 + i][kk]     = (unsigned char)(p & 0xFF);
      tile[jj * 8 + i + 1][kk] = (unsigned char)((p >> 8) & 0xFF);
    }
  }
  __syncthreads();
  const int n  = t >> 2;
  const int kc = (t & 3) * 16;
  int4 v = *(const int4*)&tile[n][kc];
  *(int4*)(bq + (size_t)(n0 + n) * K + k0 + kc) = v;
}

// dequant 16 fp8 (in uint4) * s -> 16 f16 stored at 16B-aligned dst
__device__ __forceinline__ void dq16(uint4 w, float s, __half* dst) {
  h16x2 r[8];
  const unsigned int ws[4] = {w.x, w.y, w.z, w.w};
#pragma unroll
  for (int d = 0; d < 4; ++d) {
    f32x2 lo = __builtin_amdgcn_cvt_pk_f32_fp8((int)ws[d], false);
    f32x2 hi = __builtin_amdgcn_cvt_pk_f32_fp8((int)ws[d], true);
    r[d * 2]     = __builtin_amdgcn_cvt_pkrtz(lo.x * s, lo.y * s);
    r[d * 2 + 1] = __builtin_amdgcn_cvt_pkrtz(hi.x * s, hi.y * s);
  }
  *(uint4*)dst       = *(const uint4*)&r[0];
  *(uint4*)(dst + 8) = *(const uint4*)&r[4];
}

// ============ R6: 256x256-tile, 8-wave, 4-phase/7-barrier K-loop ==========
// C[M,N] = A[M,K] @ Bq[N,K]^T (fp8 B dequant in staging, f16 MFMA).
// R5 post-mortem: MfmaUtil 29% — the dedicated dequant phase (p3) and the
// junction region serialized all 8 waves with the matrix pipe idle, and 9
// barriers/tile at 1 block/CU had no other block for coverage.
// R6: every barrier-delimited region contains an MFMA cluster; side work
// (global issues, dequant VALU+ds_write, glds staging, counted vmcnt) is
// fused INTO the MFMA windows so it schedules in the MFMA shadow:
//   p0: 12 ds_reads | issue 3 B-globals  -> MFMA(0,0)
//   p1:  4 ds_reads | dq16 x2 in-cluster -> MFMA(0,2)
//   p2:  8 ds_reads                      -> MFMA(4,0)
//   p3:  none       | STAGE_A glds + WAIT_VM(7) -> MFMA(4,2)
// vmcnt ledger: steady in-flight = {3 B-globals} + {4 A-glds} = 7; each p3
// WAIT_VM(7) drains the A-glds staged one tile earlier. Never drains to 0.
// EPI 0: C f16 = acc; EPI 1: C f16 = silu(acc)*C; EPI 2: C f32 = acc
template <int EPI>
__global__ __launch_bounds__(512, 2)
void k_gemm_q(const __half* __restrict__ A,
              const unsigned char* __restrict__ Bq,
              const float* __restrict__ sc,
              void* __restrict__ Cv, int M, int N, int K) {
  __shared__ __align__(16) __half As[2][256 * 64];   // 64 KiB, linear+xor-swz
  __shared__ __align__(16) __half Bs[2][256 * 72];   // 72 KiB, padded rows

  const int ntiles = K >> 6;  // 64 (up/gate) or 172 (down); always even

  // ---- XCD-aware swizzle, then mb-fastest (B-panel reuse in XCD L2) ----
  const int cpx = gridDim.x >> 3;
  const int bid = blockIdx.x;
  const int s2  = (bid & 7) * cpx + (bid >> 3);
  const int mb  = s2 & 15;
  const int nb  = s2 >> 4;
  const int m0 = mb << 8;
  const int n0 = nb << 8;

  const int t = threadIdx.x;
  const int w = t >> 6;         // wave 0..7
  const int lane = t & 63;
  const int quad = lane >> 4;
  const int lm = lane & 15;
  const int wm = w >> 2;        // 0..1  (row half: 128 rows)
  const int wn = w & 3;         // 0..3  (col quarter: 64 cols)

  f32x4 acc[8][4] = {};

  // ---- A staging (glds16, xor-swizzled global source) ----
  const int arow_l = w * 8 + (lane >> 3);
  const int acol_l = ((lane & 7) ^ ((lane >> 3) & 7)) * 8;  // halves
  const __half* Agl = A + (size_t)(m0 + arow_l) * K + acol_l;
#define STAGE_A(BUF, KT) do {                                        \
    const __half* _ag = Agl + (size_t)(KT) * 64;                     \
    glds16(_ag,                   (void*)&As[BUF][(w * 8) * 64]);    \
    glds16(_ag + (size_t)64 * K,  (void*)&As[BUF][(64 + w * 8) * 64]);  \
    glds16(_ag + (size_t)128 * K, (void*)&As[BUF][(128 + w * 8) * 64]); \
    glds16(_ag + (size_t)192 * K, (void*)&As[BUF][(192 + w * 8) * 64]); \
  } while (0)

  // ---- B staging (reg dequant): thread -> (row = t>>1, half = t&1) ----
  const int brow = t >> 1;
  const int bhalf = t & 1;
  const unsigned char* bgl = Bq + (size_t)(n0 + brow) * K + bhalf * 32;
  const float* spl = sc + n0 + brow;
  __half* bwr0 = &Bs[0][brow * 72 + bhalf * 32];
  __half* bwr1 = &Bs[1][brow * 72 + bhalf * 32];

  // ---- fragment read offsets ----
  const int axor = lm & 7;
  const int arb = (wm * 128 + lm) * 64;            // halves
  const int au0 = ((quad ^ axor) & 7) * 8;         // kh=0 swizzled unit
  const int au1 = (((quad ^ axor) ^ 4) & 7) * 8;   // kh=1 swizzled unit
  const int brb = (wn * 64 + lm) * 72;             // halves

#define PH_BAR __builtin_amdgcn_s_barrier()
#define PH_LGKM do { asm volatile("s_waitcnt lgkmcnt(0)" ::: "memory"); \
                     __builtin_amdgcn_sched_barrier(0); } while (0)
#define WAIT_VM(NN) do { asm volatile("s_waitcnt vmcnt(" #NN ")" ::: "memory"); \
                         } while (0)

// MFMA cluster with side-code fused inside the setprio region (same sched
// region as the MFMAs -> compiler interleaves VALU/VMEM into MFMA shadow).
#define MFMA16X(MI0, NI0, BF, XCODE) do {                                  \
    __builtin_amdgcn_s_setprio(1);                                         \
    XCODE                                                                  \
    _Pragma("unroll")                                                      \
    for (int mi = 0; mi < 4; ++mi) {                                       \
      _Pragma("unroll")                                                    \
      for (int ni = 0; ni < 2; ++ni) {                                     \
        acc[(MI0) + mi][(NI0) + ni] = __builtin_amdgcn_mfma_f32_16x16x32_f16( \
            af[mi][0], BF[ni][0], acc[(MI0) + mi][(NI0) + ni], 0, 0, 0);   \
        acc[(MI0) + mi][(NI0) + ni] = __builtin_amdgcn_mfma_f32_16x16x32_f16( \
            af[mi][1], BF[ni][1], acc[(MI0) + mi][(NI0) + ni], 0, 0, 0);   \
      }                                                                    \
    }                                                                      \
    __builtin_amdgcn_s_setprio(0);                                         \
  } while (0)

// One K-tile, 4 phases, 7 barriers. P0CODE: issue next-B globals.
// P1DQ: dequant (fills other Bs buf). P3STAGE: STAGE_A glds (refills this
// As buf for tile+2); WAIT_VM(7) drains the A-glds staged one tile ago so
// the closing barrier publishes the OTHER As buf for the next tile.
#define GEMM_TILE(ASB, BSB, P0CODE, P1DQ, P3STAGE) do {                    \
    f16x8 af[4][2], bf0[2][2], bf1[2][2];                                  \
    P0CODE                                                                 \
    __builtin_amdgcn_sched_barrier(0);                                     \
    _Pragma("unroll")                                                      \
    for (int mi = 0; mi < 4; ++mi) {                                       \
      af[mi][0] = *(const f16x8*)((ASB) + arb + mi * 1024 + au0);          \
      af[mi][1] = *(const f16x8*)((ASB) + arb + mi * 1024 + au1);          \
    }                                                                      \
    _Pragma("unroll")                                                      \
    for (int ni = 0; ni < 2; ++ni) {                                       \
      bf0[ni][0] = *(const f16x8*)((BSB) + brb + ni * 1152 + quad * 8);    \
      bf0[ni][1] = *(const f16x8*)((BSB) + brb + ni * 1152 + 32 + quad * 8); \
    }                                                                      \
    PH_BAR; PH_LGKM; MFMA16X(0, 0, bf0, {}); PH_BAR;                       \
    _Pragma("unroll")                                                      \
    for (int ni = 0; ni < 2; ++ni) {                                       \
      bf1[ni][0] = *(const f16x8*)((BSB) + brb + (2 + ni) * 1152 + quad * 8); \
      bf1[ni][1] = *(const f16x8*)((BSB) + brb + (2 + ni) * 1152 + 32 + quad * 8); \
    }                                                                      \
    PH_BAR; PH_LGKM; MFMA16X(0, 2, bf1, P1DQ); PH_BAR;                     \
    _Pragma("unroll")                                                      \
    for (int mi = 0; mi < 4; ++mi) {                                       \
      af[mi][0] = *(const f16x8*)((ASB) + 4096 + arb + mi * 1024 + au0);   \
      af[mi][1] = *(const f16x8*)((ASB) + 4096 + arb + mi * 1024 + au1);   \
    }                                                                      \
    PH_BAR; PH_LGKM; MFMA16X(4, 0, bf0, {}); PH_BAR;                       \
    MFMA16X(4, 2, bf1, P3STAGE);                                           \
    WAIT_VM(7);                                                            \
    PH_BAR;                                                                \
  } while (0)

  float sE, sO;
  uint4 bE0, bE1, bO0, bO1;

  // ---- prologue: ledger -> steady outstanding = 7 ----
  {
    float s00 = spl[0];
    uint4 a00 = *(const uint4*)(bgl);
    uint4 a01 = *(const uint4*)(bgl + 16);
    __builtin_amdgcn_sched_barrier(0);
    STAGE_A(0, 0);
    __builtin_amdgcn_sched_barrier(0);
    sO  = spl[0];                              // tile 1 is in group 0
    bO0 = *(const uint4*)(bgl + 64);
    bO1 = *(const uint4*)(bgl + 64 + 16);
    __builtin_amdgcn_sched_barrier(0);
    STAGE_A(1, 1);
    WAIT_VM(11);                               // {s00, a00, a01} landed
    dq16(a00, s00, bwr0); dq16(a01, s00, bwr0 + 16);
    WAIT_VM(7);                                // A(0) landed; 7 remain
    asm volatile("s_waitcnt lgkmcnt(0)" ::: "memory");
    PH_BAR;
  }

  for (int pt = 0; pt < ntiles; pt += 2) {
    const int tE = (pt + 2 < ntiles) ? pt + 2 : ntiles - 1;
    const int tO = (pt + 3 < ntiles) ? pt + 3 : ntiles - 1;
    // ---- even tile pt: consume As[0]/Bs[0] ----
    GEMM_TILE(As[0], Bs[0],
      { sE  = spl[(size_t)(tE >> 1) * N];
        bE0 = *(const uint4*)(bgl + tE * 64);
        bE1 = *(const uint4*)(bgl + tE * 64 + 16); },
      { dq16(bO0, sO, bwr1); dq16(bO1, sO, bwr1 + 16); },   // Bs[1] <- tile pt+1
      { STAGE_A(0, tE); });                                  // As[0] <- tile pt+2
    // ---- odd tile pt+1: consume As[1]/Bs[1] ----
    GEMM_TILE(As[1], Bs[1],
      { sO  = spl[(size_t)(tO >> 1) * N];
        bO0 = *(const uint4*)(bgl + tO * 64);
        bO1 = *(const uint4*)(bgl + tO * 64 + 16); },
      { dq16(bE0, sE, bwr0); dq16(bE1, sE, bwr0 + 16); },   // Bs[0] <- tile pt+2
      { STAGE_A(1, tO); });                                  // As[1] <- tile pt+3
  }

  // ---- epilogue: C/D layout col = lane&15, row = quad*4 + reg ----
#pragma unroll
  for (int mi = 0; mi < 8; ++mi)
#pragma unroll
    for (int ni = 0; ni < 4; ++ni)
#pragma unroll
      for (int r = 0; r < 4; ++r) {
        const int row = m0 + wm * 128 + mi * 16 + quad * 4 + r;
        const int col = n0 + wn * 64 + ni * 16 + lm;
        const float v = acc[mi][ni][r];
        if (EPI == 0) {
          ((__half*)Cv)[(size_t)row * N + col] = __float2half(v);
        } else if (EPI == 1) {
          __half* H = (__half*)Cv;
          const float u = __half2float(H[(size_t)row * N + col]);
          const float sg = v / (1.0f + __expf(-v));
          H[(size_t)row * N + col] = __float2half(sg * u);
        } else {
          ((float*)Cv)[(size_t)row * N + col] = v;
        }
      }
#undef STAGE_A
#undef PH_BAR
#undef PH_LGKM
#undef WAIT_VM
#undef MFMA16X
#undef GEMM_TILE
}

extern "C" void kernel_launch(void* const* d_in, const int* in_sizes, int n_in,
                              void* d_out, int out_size, void* d_ws, size_t ws_size,
                              hipStream_t stream) {
  const float* x   = (const float*)d_in[0];
  const int*   gqw = (const int*)d_in[1];
  const float* gsc = (const float*)d_in[2];
  const int*   gqz = (const int*)d_in[3];
  const int*   uqw = (const int*)d_in[4];
  const float* usc = (const float*)d_in[5];
  const int*   uqz = (const int*)d_in[6];
  const int*   dqw = (const int*)d_in[7];
  const float* dsc = (const float*)d_in[8];
  const int*   dqz = (const int*)d_in[9];
  float* out = (float*)d_out;

  // ws layout (~169 MB): xb (f16 x), bq (fp8 repack), h (f16 intermediate)
  char* ws = (char*)d_ws;
  __half*        xb = (__half*)ws;
  unsigned char* bq = (unsigned char*)(ws + 33554432);
  __half*        h  = (__half*)(ws + 33554432 + 45088768);

  k_f32_to_f16<<<16384, 256, 0, stream>>>((const float4*)x, (ushort4*)xb,
                                          (T_TOK * KDIM) / 4);

  dim3 rpg(IDIM / 64, KDIM / 64);    // (172, 64)
  dim3 rpd(ODIM / 64, IDIM / 64);    // (64, 172)
  const int g1 = (T_TOK / 256) * (IDIM / 256);  // 16*43 = 688 (%8==0)
  const int g2 = (T_TOK / 256) * (ODIM / 256);  // 16*16 = 256 (%8==0)

  // up: u = x @ Wu^T  -> h (f16)
  k_repack_fp8<<<rpg, 256, 0, stream>>>(uqw, uqz, bq, KDIM, IDIM);
  k_gemm_q<0><<<g1, 512, 0, stream>>>(xb, bq, usc, (void*)h, T_TOK, IDIM, KDIM);
  // gate: h = silu(x @ Wg^T) * h
  k_repack_fp8<<<rpg, 256, 0, stream>>>(gqw, gqz, bq, KDIM, IDIM);
  k_gemm_q<1><<<g1, 512, 0, stream>>>(xb, bq, gsc, (void*)h, T_TOK, IDIM, KDIM);
  // down: out = h @ Wd^T (f32)
  k_repack_fp8<<<rpd, 256, 0, stream>>>(dqw, dqz, bq, IDIM, ODIM);
  k_gemm_q<2><<<g2, 512, 0, stream>>>(h, bq, dsc, (void*)out, T_TOK, ODIM, IDIM);
}